// Round 7
// baseline (183.147 us; speedup 1.0000x reference)
//
#include <hip/hip_runtime.h>

// out[b,a,x,y] = C0 * (s x Fn)[a], Fn = periodic 4-neighbor sum of s.
// L[s][r][a] = -eps_{sra}; 6 nonzero coefficients loaded from Lp, -C0 folded in.
// Epilogue uses the EXPLICIT per-a pairing verified in rounds 1-2/6 (absmax=0.0):
//   o[0] = cA0*(sc1*Fn2) + cB0*(sc2*Fn1)
//   o[1] = cA1*(sc0*Fn2) + cB1*(sc2*Fn0)
//   o[2] = cA2*(sc0*Fn1) + cB2*(sc1*Fn0)
// (cyclic (a+1)%3 form silently sign-flips the a=1 plane - do not "simplify".)
//
// Round 7: decouple memory-level parallelism from the register allocator.
// Previous rounds proved the compiler sinks VGPR-destination loads into
// load->use chains (36 VGPR despite "hoisting"), capping per-wave outstanding
// loads at ~3 and the kernel at ~3 TB/s. global_load_lds has NO VGPR
// destination -> each wave issues ~15 async 1KB loads back-to-back;
// ~120 KB outstanding per CU. LDS slab also cuts L1 read amp to 1.25x and
// handles all y-wrap via cheap LDS indexing.

constexpr int B = 32, X = 512, Y = 512;
constexpr int XY = X * Y;
constexpr int R  = 8;        // output rows per block
constexpr int HR = R + 2;    // staged rows incl. +/-1 halo

typedef float f32x4 __attribute__((ext_vector_type(4)));

__device__ __forceinline__ void nt_store4(float* p, float a, float b, float c, float d)
{
    f32x4 v = { a, b, c, d };
    __builtin_nontemporal_store(v, (f32x4*)p);
}

__global__ __launch_bounds__(256)
void psi0_kernel(const float* __restrict__ s,
                 const float* __restrict__ C0p,
                 const float* __restrict__ Lp,
                 float* __restrict__ out)
{
    __shared__ __align__(16) float lds[HR][3][Y];   // 10*3*512*4 = 61440 B

    const int tid  = threadIdx.x;
    const int lane = tid & 63;
    const int wv   = tid >> 6;                      // 4 waves per block

    // XCD-chunked swizzle (bijective: 2048 = 8*256): adjacent slabs (which
    // share 2-row halos) land on the same XCD L2.
    const int bid = blockIdx.x;
    const int g   = (bid & 7) * 256 + (bid >> 3);
    const int b   = g >> 6;                         // 64 slabs per batch
    const int x0  = (g & 63) * R;

    const size_t base = (size_t)b * 3 * XY;

    // ---- stage HR rows x 3 comps into LDS ----
#if __has_builtin(__builtin_amdgcn_global_load_lds)
    // 30 row-comps, each 2048 B = 2 wave-level 1KB direct-to-LDS loads.
    // Wave wv handles rc = wv, wv+4, ... : all issued with no intervening
    // waits -> deep MLP independent of VGPR budget.
    for (int rc = wv; rc < HR * 3; rc += 4) {
        const int r = rc / 3, c = rc % 3;
        const int xr = (x0 + r - 1 + X) & (X - 1);
        const float* gp = s + base + (size_t)c * XY + (size_t)xr * Y;
        #pragma unroll
        for (int j = 0; j < 2; ++j) {
            __builtin_amdgcn_global_load_lds(
                (const __attribute__((address_space(1))) void*)(gp + j * 256 + lane * 4),
                (__attribute__((address_space(3))) void*)(&lds[r][c][j * 256]),
                16, 0, 0);
        }
    }
    asm volatile("s_waitcnt vmcnt(0)" ::: "memory");
#else
    for (int v = tid; v < HR * 3 * (Y / 4); v += 256) {
        const int rc = v >> 7;                 // 128 float4 per row-comp
        const int yy = (v & 127) << 2;
        const int r = rc / 3, c = rc % 3;
        const int xr = (x0 + r - 1 + X) & (X - 1);
        *(f32x4*)&lds[r][c][yy] =
            *(const f32x4*)(s + base + (size_t)c * XY + (size_t)xr * Y + yy);
    }
#endif
    __syncthreads();

    const float C0  = C0p[0];
    const float cA0 = -C0 * Lp[15];  // a=0: (s=1,r=2)
    const float cB0 = -C0 * Lp[21];  // a=0: (s=2,r=1)
    const float cA1 = -C0 * Lp[7];   // a=1: (s=0,r=2)
    const float cB1 = -C0 * Lp[19];  // a=1: (s=2,r=0)
    const float cA2 = -C0 * Lp[5];   // a=2: (s=0,r=1)
    const float cB2 = -C0 * Lp[11];  // a=2: (s=1,r=0)

    // ---- compute: 4 passes, 2 rows per pass (128 threads per row) ----
    #pragma unroll
    for (int p = 0; p < 4; ++p) {
        const int ro = (p << 1) + (tid >> 7);   // 0..7: output row in slab
        const int y0 = (tid & 127) << 2;
        const int ym = (y0 - 1) & (Y - 1);
        const int yp = (y0 + 4) & (Y - 1);

        float sc[3][4], Fn[3][4];
        #pragma unroll
        for (int c = 0; c < 3; ++c) {
            const float* lc = &lds[ro + 1][c][0];
            const f32x4 cc = *(const f32x4*)(lc + y0);
            const f32x4 uu = *(const f32x4*)(&lds[ro][c][y0]);
            const f32x4 dd = *(const f32x4*)(&lds[ro + 2][c][y0]);
            const float lf = lc[ym];
            const float rt = lc[yp];

            sc[c][0] = cc.x; sc[c][1] = cc.y; sc[c][2] = cc.z; sc[c][3] = cc.w;
            Fn[c][0] = uu.x + dd.x + lf   + cc.y;
            Fn[c][1] = uu.y + dd.y + cc.x + cc.z;
            Fn[c][2] = uu.z + dd.z + cc.y + cc.w;
            Fn[c][3] = uu.w + dd.w + cc.z + rt;
        }

        float o0[4], o1[4], o2[4];
        #pragma unroll
        for (int e = 0; e < 4; ++e) {
            o0[e] = cA0 * (sc[1][e] * Fn[2][e]) + cB0 * (sc[2][e] * Fn[1][e]);
            o1[e] = cA1 * (sc[0][e] * Fn[2][e]) + cB1 * (sc[2][e] * Fn[0][e]);
            o2[e] = cA2 * (sc[0][e] * Fn[1][e]) + cB2 * (sc[1][e] * Fn[0][e]);
        }

        const size_t ro_off = (size_t)(x0 + ro) * Y + y0;
        nt_store4(out + base + 0 * (size_t)XY + ro_off, o0[0], o0[1], o0[2], o0[3]);
        nt_store4(out + base + 1 * (size_t)XY + ro_off, o1[0], o1[1], o1[2], o1[3]);
        nt_store4(out + base + 2 * (size_t)XY + ro_off, o2[0], o2[1], o2[2], o2[3]);
    }
}

extern "C" void kernel_launch(void* const* d_in, const int* in_sizes, int n_in,
                              void* d_out, int out_size, void* d_ws, size_t ws_size,
                              hipStream_t stream)
{
    const float* s   = (const float*)d_in[0];
    // d_in[1] = t (unused: coeff is t-independent with a single cc entry)
    const float* C0p = (const float*)d_in[2];
    const float* Lp  = (const float*)d_in[3];
    float* out = (float*)d_out;

    const int blocks = B * (X / R);   // 2048 blocks x 256 threads; 8-row slab each
    psi0_kernel<<<blocks, 256, 0, stream>>>(s, C0p, Lp, out);
}

// Round 8
// 181.761 us; speedup vs baseline: 1.0076x; 1.0076x over previous
//
#include <hip/hip_runtime.h>

// out[b,a,x,y] = C0 * (s x Fn)[a], Fn = periodic 4-neighbor sum of s.
// L[s][r][a] = -eps_{sra}; 6 nonzero coefficients loaded from Lp, -C0 folded in.
// Epilogue uses the EXPLICIT per-a pairing verified in rounds 1-2/6/7 (absmax=0):
//   o[0] = cA0*(sc1*Fn2) + cB0*(sc2*Fn1)
//   o[1] = cA1*(sc0*Fn2) + cB1*(sc2*Fn0)
//   o[2] = cA2*(sc0*Fn1) + cB2*(sc1*Fn0)
// (cyclic (a+1)%3 form silently sign-flips the a=1 plane - do not "simplify".)
//
// Round 8: stream-sequentialization experiment (single variable vs round 7).
// All prior theories falsified (MLP, occupancy, reuse, store type, swizzle) -
// five structures all land 58-62us at ~3 TB/s while copy does 6.29. The one
// remaining structural difference vs copy/fill/RMSNorm: our waves hop between
// 6 planes (1MB apart) every 2KB. This round each wave's async staging loads
// cover ONE contiguous ~16KB run (component-major chunk order), and blocks run
// in natural dispatch order (consecutive blocks = consecutive slabs), so the
// memory system sees long monotone streams like the copy benchmark.

constexpr int B = 32, X = 512, Y = 512;
constexpr int XY = X * Y;
constexpr int R  = 8;        // output rows per block
constexpr int HR = R + 2;    // staged rows incl. +/-1 halo

typedef float f32x4 __attribute__((ext_vector_type(4)));

__device__ __forceinline__ void nt_store4(float* p, float a, float b, float c, float d)
{
    f32x4 v = { a, b, c, d };
    __builtin_nontemporal_store(v, (f32x4*)p);
}

__global__ __launch_bounds__(256)
void psi0_kernel(const float* __restrict__ s,
                 const float* __restrict__ C0p,
                 const float* __restrict__ Lp,
                 float* __restrict__ out)
{
    __shared__ __align__(16) float lds[HR][3][Y];   // 10*3*512*4 = 61440 B

    const int tid  = threadIdx.x;
    const int lane = tid & 63;
    const int wv   = tid >> 6;                      // 4 waves per block

    // Natural dispatch order: consecutive blocks = consecutive slabs of the
    // same batch -> chip-wide monotone advance through memory (like copy/fill).
    const int bid = blockIdx.x;
    const int b   = bid >> 6;                       // 64 slabs per batch
    const int x0  = (bid & 63) * R;

    const size_t base = (size_t)b * 3 * XY;

    // ---- stage HR rows x 3 comps into LDS, component-major per wave ----
    // chunk k = c*HR + r, k in [0,30). Wave w takes k in [8w, 8w+8) -> each
    // wave's loads are CONTIGUOUS in global memory (consecutive rows of one
    // plane, at most one plane jump per wave) instead of plane-hopping.
#if __has_builtin(__builtin_amdgcn_global_load_lds)
    {
        const int k0 = wv * 8;
        #pragma unroll
        for (int ki = 0; ki < 8; ++ki) {
            const int k = k0 + ki;
            if (k < HR * 3) {                       // wave-uniform condition
                const int c = k / HR, r = k % HR;
                const int xr = (x0 + r - 1 + X) & (X - 1);
                const float* gp = s + base + (size_t)c * XY + (size_t)xr * Y;
                #pragma unroll
                for (int j = 0; j < 2; ++j) {
                    __builtin_amdgcn_global_load_lds(
                        (const __attribute__((address_space(1))) void*)(gp + j * 256 + lane * 4),
                        (__attribute__((address_space(3))) void*)(&lds[r][c][j * 256]),
                        16, 0, 0);
                }
            }
        }
    }
    asm volatile("s_waitcnt vmcnt(0)" ::: "memory");
#else
    for (int v = tid; v < HR * 3 * (Y / 4); v += 256) {
        const int rc = v >> 7;                 // 128 float4 per row-comp
        const int yy = (v & 127) << 2;
        const int r = rc / 3, c = rc % 3;
        const int xr = (x0 + r - 1 + X) & (X - 1);
        *(f32x4*)&lds[r][c][yy] =
            *(const f32x4*)(s + base + (size_t)c * XY + (size_t)xr * Y + yy);
    }
#endif
    __syncthreads();

    const float C0  = C0p[0];
    const float cA0 = -C0 * Lp[15];  // a=0: (s=1,r=2)
    const float cB0 = -C0 * Lp[21];  // a=0: (s=2,r=1)
    const float cA1 = -C0 * Lp[7];   // a=1: (s=0,r=2)
    const float cB1 = -C0 * Lp[19];  // a=1: (s=2,r=0)
    const float cA2 = -C0 * Lp[5];   // a=2: (s=0,r=1)
    const float cB2 = -C0 * Lp[11];  // a=2: (s=1,r=0)

    // ---- compute: 4 passes, 2 rows per pass (128 threads per row) ----
    #pragma unroll
    for (int p = 0; p < 4; ++p) {
        const int ro = (p << 1) + (tid >> 7);   // 0..7: output row in slab
        const int y0 = (tid & 127) << 2;
        const int ym = (y0 - 1) & (Y - 1);
        const int yp = (y0 + 4) & (Y - 1);

        float sc[3][4], Fn[3][4];
        #pragma unroll
        for (int c = 0; c < 3; ++c) {
            const float* lc = &lds[ro + 1][c][0];
            const f32x4 cc = *(const f32x4*)(lc + y0);
            const f32x4 uu = *(const f32x4*)(&lds[ro][c][y0]);
            const f32x4 dd = *(const f32x4*)(&lds[ro + 2][c][y0]);
            const float lf = lc[ym];
            const float rt = lc[yp];

            sc[c][0] = cc.x; sc[c][1] = cc.y; sc[c][2] = cc.z; sc[c][3] = cc.w;
            Fn[c][0] = uu.x + dd.x + lf   + cc.y;
            Fn[c][1] = uu.y + dd.y + cc.x + cc.z;
            Fn[c][2] = uu.z + dd.z + cc.y + cc.w;
            Fn[c][3] = uu.w + dd.w + cc.z + rt;
        }

        float o0[4], o1[4], o2[4];
        #pragma unroll
        for (int e = 0; e < 4; ++e) {
            o0[e] = cA0 * (sc[1][e] * Fn[2][e]) + cB0 * (sc[2][e] * Fn[1][e]);
            o1[e] = cA1 * (sc[0][e] * Fn[2][e]) + cB1 * (sc[2][e] * Fn[0][e]);
            o2[e] = cA2 * (sc[0][e] * Fn[1][e]) + cB2 * (sc[1][e] * Fn[0][e]);
        }

        const size_t ro_off = (size_t)(x0 + ro) * Y + y0;
        nt_store4(out + base + 0 * (size_t)XY + ro_off, o0[0], o0[1], o0[2], o0[3]);
        nt_store4(out + base + 1 * (size_t)XY + ro_off, o1[0], o1[1], o1[2], o1[3]);
        nt_store4(out + base + 2 * (size_t)XY + ro_off, o2[0], o2[1], o2[2], o2[3]);
    }
}

extern "C" void kernel_launch(void* const* d_in, const int* in_sizes, int n_in,
                              void* d_out, int out_size, void* d_ws, size_t ws_size,
                              hipStream_t stream)
{
    const float* s   = (const float*)d_in[0];
    // d_in[1] = t (unused: coeff is t-independent with a single cc entry)
    const float* C0p = (const float*)d_in[2];
    const float* Lp  = (const float*)d_in[3];
    float* out = (float*)d_out;

    const int blocks = B * (X / R);   // 2048 blocks x 256 threads; 8-row slab each
    psi0_kernel<<<blocks, 256, 0, stream>>>(s, C0p, Lp, out);
}